// Round 7
// baseline (91.169 us; speedup 1.0000x reference)
//
#include <hip/hip_runtime.h>

// QOuter: out_rr[b,i,j] = real[b,i]*real[b,j] + imag[b,i]*imag[b,j]
//         out_ii[b,i,j] = imag[b,i]*real[b,j] - real[b,i]*imag[b,j]
// B=64, N=1024. Outputs concatenated flat: [out_rr (B*N*N), out_ii (B*N*N)].
// Store-BW bound. Round 7: keep the R6 winner (1 NT store/thread) but use
// 1024-thread blocks: each block = rr+ii rows for TWO consecutive i values.
// 32768 blocks. Waves 0-1: rr row i0; waves 2-3: ii row i0; 4-5: rr i0+1;
// 6-7: ii i0+1 (all wave-uniform decode).

typedef float f32x4 __attribute__((ext_vector_type(4)));

constexpr int B_ = 64;
constexpr int N_ = 1024;

__global__ __launch_bounds__(1024) void qouter_kernel(
    const float* __restrict__ real,
    const float* __restrict__ imag,
    float* __restrict__ out) {
    const int blk  = blockIdx.x;            // 0 .. B*N/2 - 1
    const int b    = blk >> 9;              // blk / 512  (512 row-pairs per b)
    const int t    = threadIdx.x;
    const int ri   = t >> 9;                // 0/1: which of the two rows
    const int half = (t >> 8) & 1;          // 0: out_rr, 1: out_ii (wave-uniform)
    const int j4   = t & 255;               // float4 column index

    const int bi = (blk << 1) | ri;         // global row index b*N + i

    // Row scalars (wave-uniform -> scalar path) and row vectors (L1/L2-hot)
    const float rc = real[bi];
    const float ic = imag[bi];
    const f32x4 rj = reinterpret_cast<const f32x4*>(real + (size_t)b * N_)[j4];
    const f32x4 ij = reinterpret_cast<const f32x4*>(imag + (size_t)b * N_)[j4];

    const f32x4 o = half ? (ic * rj - rc * ij)    // out_ii
                         : (rc * rj + ic * ij);   // out_rr

    const size_t f4 = (size_t)bi * (N_ / 4) + j4
                    + (size_t)half * ((size_t)B_ * N_ * (N_ / 4));
    __builtin_nontemporal_store(o, reinterpret_cast<f32x4*>(out) + f4);
}

extern "C" void kernel_launch(void* const* d_in, const int* in_sizes, int n_in,
                              void* d_out, int out_size, void* d_ws, size_t ws_size,
                              hipStream_t stream) {
    const float* real = (const float*)d_in[0];
    const float* imag = (const float*)d_in[1];
    float* out = (float*)d_out;

    dim3 grid(B_ * N_ / 2);   // 32768 blocks, one per pair of rows
    dim3 block(1024);         // 4 rows' worth of float4 stores (2x rr + 2x ii)
    qouter_kernel<<<grid, block, 0, stream>>>(real, imag, out);
}

// Round 8
// 84.388 us; speedup vs baseline: 1.0804x; 1.0804x over previous
//
#include <hip/hip_runtime.h>

// QOuter: out_rr[b,i,j] = real[b,i]*real[b,j] + imag[b,i]*imag[b,j]
//         out_ii[b,i,j] = imag[b,i]*real[b,j] - real[b,i]*imag[b,j]
// B=64, N=1024. Outputs concatenated flat: [out_rr (B*N*N), out_ii (B*N*N)].
// Store-BW bound. Round 8: 1 NT store/thread (R6 winner property) at block
// width 256 (fill's shape). 131072 blocks; consecutive blocks = rr then ii
// row of the same (b,i), keeping dispatch-order stores address-clustered.

typedef float f32x4 __attribute__((ext_vector_type(4)));

constexpr int B_ = 64;
constexpr int N_ = 1024;

__global__ __launch_bounds__(256) void qouter_kernel(
    const float* __restrict__ real,
    const float* __restrict__ imag,
    float* __restrict__ out) {
    const int blk  = blockIdx.x;            // 0 .. 2*B*N - 1
    const int bi   = blk >> 1;              // row index b*N + i
    const int half = blk & 1;               // 0: out_rr, 1: out_ii
    const int b    = bi >> 10;              // bi / N
    const int j4   = threadIdx.x;           // float4 column index 0..255

    // Row scalars (block-uniform -> scalar path) and row vectors (L1/L2-hot)
    const float rc = real[bi];
    const float ic = imag[bi];
    const f32x4 rj = reinterpret_cast<const f32x4*>(real + (size_t)b * N_)[j4];
    const f32x4 ij = reinterpret_cast<const f32x4*>(imag + (size_t)b * N_)[j4];

    const f32x4 o = half ? (ic * rj - rc * ij)    // out_ii
                         : (rc * rj + ic * ij);   // out_rr

    const size_t f4 = (size_t)bi * (N_ / 4) + j4
                    + (size_t)half * ((size_t)B_ * N_ * (N_ / 4));
    __builtin_nontemporal_store(o, reinterpret_cast<f32x4*>(out) + f4);
}

extern "C" void kernel_launch(void* const* d_in, const int* in_sizes, int n_in,
                              void* d_out, int out_size, void* d_ws, size_t ws_size,
                              hipStream_t stream) {
    const float* real = (const float*)d_in[0];
    const float* imag = (const float*)d_in[1];
    float* out = (float*)d_out;

    dim3 grid(2 * B_ * N_);   // 131072 blocks: one row (rr or ii) each
    dim3 block(256);          // 256 threads x float4 = 1024 columns
    qouter_kernel<<<grid, block, 0, stream>>>(real, imag, out);
}